// Round 6
// baseline (335.722 us; speedup 1.0000x reference)
//
#include <hip/hip_runtime.h>

typedef short bf16x8 __attribute__((ext_vector_type(8)));
typedef float f32x4 __attribute__((ext_vector_type(4)));
typedef unsigned short u16x4 __attribute__((ext_vector_type(4)));

__device__ __forceinline__ unsigned short f2b(float f) {
    unsigned int u = __builtin_bit_cast(unsigned int, f);
    u += 0x7fffu + ((u >> 16) & 1u);   // RNE
    return (unsigned short)(u >> 16);
}
__device__ __forceinline__ float b2f(unsigned short s) {
    unsigned int u = ((unsigned int)s) << 16;
    return __builtin_bit_cast(float, u);
}

// wt[k][i][j] = bf16(w1[j][k][i]);  k<3, i<128, j<64
__global__ void wt_prepass(const float* __restrict__ w1, unsigned short* __restrict__ wt) {
    int t = blockIdx.x * 256 + threadIdx.x;
    if (t >= 24576) return;
    int j = t & 63;
    int i = (t >> 6) & 127;
    int k = t >> 13;
    wt[t] = f2b(w1[(j * 3 + k) * 128 + i]);
}

// xs row = a*13 + s; byte = (row<<7) + ((j*2) ^ ((row&7)<<4))
// t4s: [ic][r], 456 B per ic;  byte = ic*456 + ((r*2) ^ (((r>>5)&7)<<3))
//   (XOR scoped to r-dim only -> injective; bits 5..7 of r untouched by XOR)

__global__ __launch_bounds__(256, 3) void fused_main(
        const float* __restrict__ x, const float* __restrict__ w0,
        const unsigned short* __restrict__ wt, float* __restrict__ y) {
    __shared__ __align__(16) char smem[364 * 128];   // 46592 B: xs, later t4s
    __shared__ float w0s[256];

    const int tid  = threadIdx.x;
    const int lane = tid & 63;
    const int w    = tid >> 6;
    const int rl   = lane & 15;
    const int jb0  = (lane >> 4) << 3;

    // same-XCD sibling mapping: XCD (B&7) processes b-range [128*xcd, ...),
    // the 4 bc-siblings of one b are 8 dispatch-slots apart (concurrent).
    const int B   = (int)blockIdx.x;
    const int b   = ((B & 7) << 7) + ((B >> 3) >> 2);
    const int bc  = (B >> 3) & 3;
    const int c0  = 7 * bc;

    w0s[tid] = w0[tid];

    // ---- zero-fill halo slots (bc0: s=0,11 ; bc3: s=9) ----
    {
        int nh = (bc == 0) ? 2 : ((bc == 3) ? 1 : 0);
        for (int idx = tid; idx < nh * 224; idx += 256) {
            int rr = idx;
            int sl;
            if (bc == 0) {
                if (rr >= 224) { sl = 11; rr -= 224; } else sl = 0;
            } else {
                sl = 9;                 // bc == 3
            }
            int a   = rr >> 3, ch = rr & 7;
            int row = a * 13 + sl;
            int byte = (row << 7) + ((ch << 4) ^ ((row & 7) << 4));
            *reinterpret_cast<f32x4*>(smem + byte) = f32x4{0.f, 0.f, 0.f, 0.f};
        }
    }

    // ---- staging: windowed 3-quad float4 reads -> swizzled xs ----
    int q0, q1, q2;
    if      (bc == 0) { q0 = 0; q1 = 1; q2 = 6; }
    else if (bc == 1) { q0 = 1; q1 = 2; q2 = 3; }
    else if (bc == 2) { q0 = 3; q1 = 4; q2 = 5; }
    else              { q0 = 4; q1 = 5; q2 = 6; }

    const float* xb = x + (size_t)b * (1792 * 28);
    for (int it = 0; it < 21; ++it) {
        int f  = tid + (it << 8);          // 21*256 = 5376 = 1792 rows * 3 quads
        int R  = f / 3;
        int q3 = f - R * 3;
        int q  = (q3 == 0) ? q0 : ((q3 == 1) ? q1 : q2);
        int a  = R % 28;
        int j  = R / 28;
        const float4 v = *reinterpret_cast<const float4*>(xb + R * 28 + (q << 2));
        int j2 = j << 1;
        float vv[4] = {v.x, v.y, v.z, v.w};
#pragma unroll
        for (int u = 0; u < 4; ++u) {
            int n = (q << 2) + u;
            int sl; bool ok;
            if (bc == 0) {
                if (n < 8)       { sl = n + 1;  ok = true; }
                else if (n >= 26){ sl = n - 17; ok = true; }
                else             { sl = 0;      ok = false; }
            } else {
                sl = n + 2 - c0;
                ok = (unsigned)sl < 10u;
            }
            if (ok) {
                int row  = a * 13 + sl;
                int byte = (row << 7) + (j2 ^ ((row & 7) << 4));
                *(unsigned short*)(smem + byte) = f2b(vv[u]);
            }
        }
    }
    __syncthreads();

    // ---- K-loop: per wave 14 m-tiles x 2 n-tiles, 6 K-steps of 32 ----
    const int cl = rl & 7;
    const int rh = rl >> 3;
    int rowoff[3];
#pragma unroll
    for (int k = 0; k < 3; ++k) {
        int sIdx = (bc == 0) ? ((cl == 0) ? (9 + k) : (cl - 1 + k)) : (cl + k);
        rowoff[k] = rh * 13 + sIdx;
    }

    f32x4 acc[14][2];
#pragma unroll
    for (int mt = 0; mt < 14; ++mt) {
        acc[mt][0] = f32x4{0.f, 0.f, 0.f, 0.f};
        acc[mt][1] = f32x4{0.f, 0.f, 0.f, 0.f};
    }

#pragma unroll
    for (int s = 0; s < 6; ++s) {
        const int k  = s >> 1;
        const int jb = ((s & 1) << 5) + jb0;
        const int jx = jb << 1;
        bf16x8 b0 = *reinterpret_cast<const bf16x8*>(wt + (k << 13) + (((w << 5) + rl) << 6) + jb);
        bf16x8 b1 = *reinterpret_cast<const bf16x8*>(wt + (k << 13) + (((w << 5) + 16 + rl) << 6) + jb);
#pragma unroll
        for (int mt = 0; mt < 14; ++mt) {
            int row  = 26 * mt + rowoff[k];
            int byte = (row << 7) + (jx ^ ((row & 7) << 4));
            bf16x8 af = *reinterpret_cast<const bf16x8*>(smem + byte);
            acc[mt][0] = __builtin_amdgcn_mfma_f32_16x16x32_bf16(af, b0, acc[mt][0], 0, 0, 0);
            acc[mt][1] = __builtin_amdgcn_mfma_f32_16x16x32_bf16(af, b1, acc[mt][1], 0, 0, 0);
        }
    }
    __syncthreads();

    // ---- epilogue: two i-halves; t4s [ic][r] pitch 456 B, r-scoped XOR swizzle ----
    const int rq = (lane >> 4) << 2;
#pragma unroll
    for (int h = 0; h < 2; ++h) {
        if ((w >> 1) == h) {
            int icb = ((w & 1) << 5) + rl;
#pragma unroll
            for (int mt = 0; mt < 14; ++mt) {
                int rbase = (mt << 4) + rq;
                int roff  = (rbase << 1) ^ (((rbase >> 5) & 7) << 3);
#pragma unroll
                for (int p = 0; p < 2; ++p) {
                    int ic = icb + (p << 4);
                    u16x4 pk;
                    pk.x = f2b(acc[mt][p][0]);
                    pk.y = f2b(acc[mt][p][1]);
                    pk.z = f2b(acc[mt][p][2]);
                    pk.w = f2b(acc[mt][p][3]);
                    *reinterpret_cast<u16x4*>(smem + ic * 456 + roff) = pk;
                }
            }
        }
        __syncthreads();
        for (int f = tid; f < 3136; f += 256) {
            int lq    = f % 7;
            int t1    = f / 7;
            int m_loc = t1 % 7;
            int iloc  = t1 / 7;
            int i = (h << 6) + iloc;
            float w00 = w0s[2 * i], w01 = w0s[2 * i + 1];
            int m = c0 + m_loc;
            float ov[4];
#pragma unroll
            for (int u = 0; u < 4; ++u) {
                int l  = (lq << 2) + u;
                int ap = (l == 0) ? 27 : (l - 1);
                int r2 = (ap << 3) + m_loc;        // c = m-1 (cyclic via block map)
                int r1 = r2 + 1;                   // c = m
                int by1 = iloc * 456 + ((r1 << 1) ^ (((r1 >> 5) & 7) << 3));
                int by2 = iloc * 456 + ((r2 << 1) ^ (((r2 >> 5) & 7) << 3));
                float v1 = b2f(*(unsigned short*)(smem + by1));
                float v2 = b2f(*(unsigned short*)(smem + by2));
                ov[u] = w00 * v1 + w01 * v2;
            }
            float4 o; o.x = ov[0]; o.y = ov[1]; o.z = ov[2]; o.w = ov[3];
            *reinterpret_cast<float4*>(y + ((((size_t)b * 128 + i) * 28 + m) * 28) + (lq << 2)) = o;
        }
        __syncthreads();
    }
}

extern "C" void kernel_launch(void* const* d_in, const int* in_sizes, int n_in,
                              void* d_out, int out_size, void* d_ws, size_t ws_size,
                              hipStream_t stream) {
    const float* x  = (const float*)d_in[0];
    const float* w0 = (const float*)d_in[1];
    const float* w1 = (const float*)d_in[2];
    float* y = (float*)d_out;
    unsigned short* wt = (unsigned short*)d_ws;   // 24576 u16 = 48 KiB

    hipLaunchKernelGGL(wt_prepass, dim3(96), dim3(256), 0, stream, w1, wt);
    hipLaunchKernelGGL(fused_main, dim3(4096), dim3(256), 0, stream, x, w0, wt, y);
}

// Round 7
// 221.397 us; speedup vs baseline: 1.5164x; 1.5164x over previous
//
#include <hip/hip_runtime.h>

typedef short bf16x8 __attribute__((ext_vector_type(8)));
typedef float f32x4 __attribute__((ext_vector_type(4)));

__device__ __forceinline__ unsigned short f2b(float f) {
    unsigned int u = __builtin_bit_cast(unsigned int, f);
    u += 0x7fffu + ((u >> 16) & 1u);   // RNE
    return (unsigned short)(u >> 16);
}
__device__ __forceinline__ float b2f(unsigned short s) {
    unsigned int u = ((unsigned int)s) << 16;
    return __builtin_bit_cast(float, u);
}

// wt[k][i][j] = bf16(w1[j][k][i]);  k<3, i<128, j<64
__global__ void wt_prepass(const float* __restrict__ w1, unsigned short* __restrict__ wt) {
    int t = blockIdx.x * 256 + threadIdx.x;
    if (t >= 24576) return;
    int j = t & 63;
    int i = (t >> 6) & 127;
    int k = t >> 13;
    wt[t] = f2b(w1[(j * 3 + k) * 128 + i]);
}

// xs: row = a*13 + s; byte = (row<<7) + ((j*2) ^ ((row&7)<<4))   [rows 0..363]
// t4s: [ic 0..127][cl 0..7][ap 0..27] u16, byte = ic*464 + cl*58 + ap*2  (59,392 B)

__global__ __launch_bounds__(256, 2) void fused_main(
        const float* __restrict__ x, const float* __restrict__ w0,
        const unsigned short* __restrict__ wt, float* __restrict__ y) {
    __shared__ __align__(16) char smem[128 * 464];   // 59,392 B: xs (46.6K) then t4s
    __shared__ float w0s[256];

    const int tid  = threadIdx.x;
    const int lane = tid & 63;
    const int w    = tid >> 6;
    const int rl   = lane & 15;
    const int jb0  = (lane >> 4) << 3;

    // same-XCD sibling mapping (bc-siblings of one b are 8 dispatch-slots apart)
    const int B   = (int)blockIdx.x;
    const int b   = ((B & 7) << 7) + ((B >> 3) >> 2);
    const int bc  = (B >> 3) & 3;
    const int c0  = 7 * bc;

    w0s[tid] = w0[tid];

    // ---- zero-fill halo slots (bc0: s=0,11 ; bc3: s=9) ----
    {
        int nh = (bc == 0) ? 2 : ((bc == 3) ? 1 : 0);
        for (int idx = tid; idx < nh * 224; idx += 256) {
            int rr = idx;
            int sl;
            if (bc == 0) {
                if (rr >= 224) { sl = 11; rr -= 224; } else sl = 0;
            } else {
                sl = 9;                 // bc == 3
            }
            int a   = rr >> 3, ch = rr & 7;
            int row = a * 13 + sl;
            int byte = (row << 7) + ((ch << 4) ^ ((row & 7) << 4));
            *reinterpret_cast<f32x4*>(smem + byte) = f32x4{0.f, 0.f, 0.f, 0.f};
        }
    }

    // ---- staging: 3 batches of 7 independent float4 loads -> scatter ----
    int q0, q1, q2;
    if      (bc == 0) { q0 = 0; q1 = 1; q2 = 6; }
    else if (bc == 1) { q0 = 1; q1 = 2; q2 = 3; }
    else if (bc == 2) { q0 = 3; q1 = 4; q2 = 5; }
    else              { q0 = 4; q1 = 5; q2 = 6; }

    const float* xb = x + (size_t)b * (1792 * 28);
    for (int bt = 0; bt < 3; ++bt) {
        float4 vbuf[7];
#pragma unroll
        for (int u = 0; u < 7; ++u) {
            int f  = tid + (((bt * 7) + u) << 8);
            int R  = f / 3;
            int q3 = f - R * 3;
            int q  = (q3 == 0) ? q0 : ((q3 == 1) ? q1 : q2);
            vbuf[u] = *reinterpret_cast<const float4*>(xb + R * 28 + (q << 2));
        }
#pragma unroll
        for (int u = 0; u < 7; ++u) {
            int f  = tid + (((bt * 7) + u) << 8);
            int R  = f / 3;
            int q3 = f - R * 3;
            int q  = (q3 == 0) ? q0 : ((q3 == 1) ? q1 : q2);
            int a  = R % 28;
            int j2 = (R / 28) << 1;
            float vv[4] = {vbuf[u].x, vbuf[u].y, vbuf[u].z, vbuf[u].w};
#pragma unroll
            for (int e = 0; e < 4; ++e) {
                int n = (q << 2) + e;
                int sl; bool ok;
                if (bc == 0) {
                    if (n < 8)        { sl = n + 1;  ok = true; }
                    else if (n >= 26) { sl = n - 17; ok = true; }
                    else              { sl = 0;      ok = false; }
                } else {
                    sl = n + 2 - c0;
                    ok = (unsigned)sl < 10u;
                }
                if (ok) {
                    int row  = a * 13 + sl;
                    int byte = (row << 7) + (j2 ^ ((row & 7) << 4));
                    *(unsigned short*)(smem + byte) = f2b(vv[e]);
                }
            }
        }
    }
    __syncthreads();

    // ---- K-loop: per wave 14 m-tiles x 2 n-tiles, 6 K-steps of 32 ----
    const int cl = rl & 7;
    const int rh = rl >> 3;
    int rowoff[3];
#pragma unroll
    for (int k = 0; k < 3; ++k) {
        int sIdx = (bc == 0) ? ((cl == 0) ? (9 + k) : (cl - 1 + k)) : (cl + k);
        rowoff[k] = rh * 13 + sIdx;
    }

    f32x4 acc[14][2];
#pragma unroll
    for (int mt = 0; mt < 14; ++mt) {
        acc[mt][0] = f32x4{0.f, 0.f, 0.f, 0.f};
        acc[mt][1] = f32x4{0.f, 0.f, 0.f, 0.f};
    }

#pragma unroll
    for (int s = 0; s < 6; ++s) {
        const int k  = s >> 1;
        const int jb = ((s & 1) << 5) + jb0;
        const int jx = jb << 1;
        bf16x8 b0 = *reinterpret_cast<const bf16x8*>(wt + (k << 13) + (((w << 5) + rl) << 6) + jb);
        bf16x8 b1 = *reinterpret_cast<const bf16x8*>(wt + (k << 13) + (((w << 5) + 16 + rl) << 6) + jb);
#pragma unroll
        for (int mt = 0; mt < 14; ++mt) {
            int row  = 26 * mt + rowoff[k];
            int byte = (row << 7) + (jx ^ ((row & 7) << 4));
            bf16x8 af = *reinterpret_cast<const bf16x8*>(smem + byte);
            acc[mt][0] = __builtin_amdgcn_mfma_f32_16x16x32_bf16(af, b0, acc[mt][0], 0, 0, 0);
            acc[mt][1] = __builtin_amdgcn_mfma_f32_16x16x32_bf16(af, b1, acc[mt][1], 0, 0, 0);
        }
    }
    __syncthreads();

    // ---- epilogue: single phase; t4s[ic][cl][ap] ----
    {
        const int rq  = (lane >> 4) << 2;
        const int icb = (w << 5) + rl;
#pragma unroll
        for (int mt = 0; mt < 14; ++mt) {
            int rbase = (mt << 4) + rq;
            int a2    = (rbase >> 3) << 1;      // ap byte offset
            int clb   = rbase & 7;              // 0 or 4
#pragma unroll
            for (int p = 0; p < 2; ++p) {
                int ic   = icb + (p << 4);
                int base = ic * 464 + a2;
#pragma unroll
                for (int q = 0; q < 4; ++q) {
                    *(unsigned short*)(smem + base + (clb + q) * 58) = f2b(acc[mt][p][q]);
                }
            }
        }
    }
    __syncthreads();

    for (int f = tid; f < 6272; f += 256) {
        int lq    = f % 7;
        int t1    = f / 7;
        int m_loc = t1 % 7;
        int iloc  = t1 / 7;                     // full 0..127
        float w00 = w0s[2 * iloc], w01 = w0s[2 * iloc + 1];
        int m     = c0 + m_loc;
        int base1 = iloc * 464 + (m_loc + 1) * 58;   // c = m
        int base2 = iloc * 464 + m_loc * 58;         // c = m-1
        float ov[4];
#pragma unroll
        for (int u = 0; u < 4; ++u) {
            int l  = (lq << 2) + u;
            int ap = (l == 0) ? 27 : (l - 1);
            float v1 = b2f(*(unsigned short*)(smem + base1 + (ap << 1)));
            float v2 = b2f(*(unsigned short*)(smem + base2 + (ap << 1)));
            ov[u] = w00 * v1 + w01 * v2;
        }
        float4 o; o.x = ov[0]; o.y = ov[1]; o.z = ov[2]; o.w = ov[3];
        *reinterpret_cast<float4*>(y + ((((size_t)b * 128 + iloc) * 28 + m) * 28) + (lq << 2)) = o;
    }
}

extern "C" void kernel_launch(void* const* d_in, const int* in_sizes, int n_in,
                              void* d_out, int out_size, void* d_ws, size_t ws_size,
                              hipStream_t stream) {
    const float* x  = (const float*)d_in[0];
    const float* w0 = (const float*)d_in[1];
    const float* w1 = (const float*)d_in[2];
    float* y = (float*)d_out;
    unsigned short* wt = (unsigned short*)d_ws;   // 24576 u16 = 48 KiB

    hipLaunchKernelGGL(wt_prepass, dim3(96), dim3(256), 0, stream, w1, wt);
    hipLaunchKernelGGL(fused_main, dim3(4096), dim3(256), 0, stream, x, w0, wt, y);
}